// Round 1
// baseline (276.708 us; speedup 1.0000x reference)
//
#include <hip/hip_runtime.h>
#include <hip/hip_bf16.h>

typedef __bf16 bf16_t;
typedef __bf16 bf16x4 __attribute__((ext_vector_type(4)));
typedef __bf16 bf16x8 __attribute__((ext_vector_type(8)));
typedef float  f32x4  __attribute__((ext_vector_type(4)));

// ---------------------------------------------------------------- helpers
__device__ __forceinline__ void gload_lds16(const void* g, void* l)
{
    __builtin_amdgcn_global_load_lds((__attribute__((address_space(1))) void*)g,
                                     (__attribute__((address_space(3))) void*)l,
                                     16, 0, 0);
}

// ---------------------------------------------------------------- fp32 -> bf16 cast (vectorized)
__global__ __launch_bounds__(256) void cast_bf16_k(const float* __restrict__ in, bf16_t* __restrict__ out)
{
    size_t i = ((size_t)blockIdx.x * 256 + threadIdx.x) * 4;
    f32x4 v = *(const f32x4*)(in + i);
    bf16x4 o;
    o[0] = (bf16_t)v[0]; o[1] = (bf16_t)v[1]; o[2] = (bf16_t)v[2]; o[3] = (bf16_t)v[3];
    *(bf16x4*)(out + i) = o;
}

// ---------------------------------------------------------------- NT GEMM: C[m,n] = sum_k A[m,k]*B[n,k] + bias[n]
// 128x128 tile, BK=64, 4 waves (2x2), each wave 64x64 via 4x4 frags of 16x16x32 MFMA.
// B batching: for sim GEMM, B advances by b_batch_stride when m0 crosses rows_per_batch.
__global__ __launch_bounds__(256) void gemm_bt(
    const bf16_t* __restrict__ A, const bf16_t* __restrict__ B,
    const float* __restrict__ bias, float* __restrict__ C,
    int N, int K, int rows_per_batch, long long b_batch_stride)
{
    __shared__ bf16_t lsA[128 * 64];
    __shared__ bf16_t lsB[128 * 64];
    const int tid  = threadIdx.x;
    const int lane = tid & 63;
    const int wave = tid >> 6;
    const int wm   = (wave >> 1) * 64;
    const int wn   = (wave & 1) * 64;
    const int m0   = blockIdx.y * 128;
    const int n0   = blockIdx.x * 128;
    const bf16_t* Bb = B + (long long)(m0 / rows_per_batch) * b_batch_stride;

    f32x4 acc[4][4] = {};

    const int srow = tid >> 3;        // staging: 256 threads cover 32 rows x 8 chunks of 16B
    const int scol = (tid & 7) * 8;   // element offset within BK
    for (int kt = 0; kt < K; kt += 64) {
#pragma unroll
        for (int i = 0; i < 4; ++i) {
            const int r = i * 32 + srow;
            // LDS byte offset = i*4096 + tid*16 -> wave-uniform base + lane*16 (linear dest, required)
            gload_lds16(A  + (size_t)(m0 + r) * K + kt + scol, lsA + r * 64 + scol);
            gload_lds16(Bb + (size_t)(n0 + r) * K + kt + scol, lsB + r * 64 + scol);
        }
        __syncthreads();  // compiler drains vmcnt before barrier
#pragma unroll
        for (int ks = 0; ks < 2; ++ks) {
            const int kk = ks * 32 + (lane >> 4) * 8;
            bf16x8 af[4], bfr[4];
#pragma unroll
            for (int f = 0; f < 4; ++f) {
                af[f]  = *(const bf16x8*)&lsA[(wm + f * 16 + (lane & 15)) * 64 + kk];
                bfr[f] = *(const bf16x8*)&lsB[(wn + f * 16 + (lane & 15)) * 64 + kk];
            }
#pragma unroll
            for (int fm = 0; fm < 4; ++fm)
#pragma unroll
                for (int fn = 0; fn < 4; ++fn)
                    acc[fm][fn] = __builtin_amdgcn_mfma_f32_16x16x32_bf16(af[fm], bfr[fn], acc[fm][fn], 0, 0, 0);
        }
        __syncthreads();
    }
    // C/D layout: col = lane&15, row = (lane>>4)*4 + reg   [m89-verified]
#pragma unroll
    for (int fm = 0; fm < 4; ++fm) {
        const int rb = m0 + wm + fm * 16 + ((lane >> 4) << 2);
#pragma unroll
        for (int fn = 0; fn < 4; ++fn) {
            const int col = n0 + wn + fn * 16 + (lane & 15);
            const float bv = bias ? bias[col] : 0.0f;
#pragma unroll
            for (int r = 0; r < 4; ++r)
                C[(size_t)(rb + r) * N + col] = acc[fm][fn][r] + bv;
        }
    }
}

// ---------------------------------------------------------------- BN stats (per branch, per column), two stage
__global__ __launch_bounds__(256) void bn_part(const float* __restrict__ h, float* __restrict__ ps, float* __restrict__ ps2)
{
    const int s  = blockIdx.x & 3;        // row segment (512 rows)
    const int g  = blockIdx.x >> 2;       // 0..63
    const int br = g >> 5;
    const int col = (g & 31) * 64 + (threadIdx.x & 63);
    const int rg  = threadIdx.x >> 6;     // 0..3 (128 rows each)
    const float* p = h + (size_t)br * 2048 * 2048;
    const int r0 = s * 512 + rg * 128;
    float a = 0.f, b = 0.f;
    for (int r = r0; r < r0 + 128; ++r) {
        float v = p[(size_t)r * 2048 + col];
        a += v; b += v * v;
    }
    __shared__ float SA[256], SB[256];
    SA[threadIdx.x] = a; SB[threadIdx.x] = b;
    __syncthreads();
    if (rg == 0) {
        const int t = threadIdx.x;
        a = SA[t] + SA[t + 64] + SA[t + 128] + SA[t + 192];
        b = SB[t] + SB[t + 64] + SB[t + 128] + SB[t + 192];
        ps [s * 4096 + br * 2048 + col] = a;
        ps2[s * 4096 + br * 2048 + col] = b;
    }
}

__global__ __launch_bounds__(256) void bn_final(const float* __restrict__ ps, const float* __restrict__ ps2,
                                                float* __restrict__ mu, float* __restrict__ rinv)
{
    const int c = blockIdx.x * 256 + threadIdx.x;  // 0..4095
    float s  = ps[c]  + ps[c + 4096]  + ps[c + 8192]  + ps[c + 12288];
    float s2 = ps2[c] + ps2[c + 4096] + ps2[c + 8192] + ps2[c + 12288];
    float m = s * (1.0f / 2048.0f);
    float v = s2 * (1.0f / 2048.0f) - m * m;   // biased var, matches jnp .var(0)
    mu[c]   = m;
    rinv[c] = rsqrtf(v + 1e-5f);
}

// ---------------------------------------------------------------- BN apply + ReLU + cast to bf16
__global__ __launch_bounds__(256) void bn_apply(const float* __restrict__ h, const float* __restrict__ mu,
                                                const float* __restrict__ rinv, const float* __restrict__ gamma,
                                                const float* __restrict__ beta, bf16_t* __restrict__ out)
{
    const size_t base = ((size_t)blockIdx.x * 256 + threadIdx.x) * 4;
    const int row = (int)(base >> 11);
    const int col = (int)(base & 2047);
    const int br  = row >> 11;
    f32x4 v = *(const f32x4*)(h + base);
    bf16x4 o;
#pragma unroll
    for (int j = 0; j < 4; ++j) {
        const int c = col + j;
        float t = (v[j] - mu[br * 2048 + c]) * rinv[br * 2048 + c] * gamma[c] + beta[c];
        o[j] = (bf16_t)fmaxf(t, 0.0f);
    }
    *(bf16x4*)(out + base) = o;
}

// ---------------------------------------------------------------- row L2-normalize + cast to bf16
__global__ __launch_bounds__(256) void rownorm(const float* __restrict__ o, bf16_t* __restrict__ feat)
{
    const int row = blockIdx.x;
    const int t = threadIdx.x;
    const float* p = o + (size_t)row * 2048;
    f32x4 v0 = *(const f32x4*)(p + t * 4);
    f32x4 v1 = *(const f32x4*)(p + 1024 + t * 4);
    float ss = v0[0]*v0[0] + v0[1]*v0[1] + v0[2]*v0[2] + v0[3]*v0[3]
             + v1[0]*v1[0] + v1[1]*v1[1] + v1[2]*v1[2] + v1[3]*v1[3];
    __shared__ float S[256];
    S[t] = ss;
    __syncthreads();
    for (int off = 128; off; off >>= 1) { if (t < off) S[t] += S[t + off]; __syncthreads(); }
    const float rn = 1.0f / fmaxf(sqrtf(S[0]), 1e-12f);
    bf16x4 o0, o1;
#pragma unroll
    for (int j = 0; j < 4; ++j) { o0[j] = (bf16_t)(v0[j] * rn); o1[j] = (bf16_t)(v1[j] * rn); }
    *(bf16x4*)(feat + (size_t)row * 2048 + t * 4) = o0;
    *(bf16x4*)(feat + (size_t)row * 2048 + 1024 + t * 4) = o1;
}

// ---------------------------------------------------------------- per-row argmax (excluding diagonal, first-index ties)
__global__ __launch_bounds__(256) void rowargmax(const float* __restrict__ sim, int* __restrict__ y)
{
    const int row = blockIdx.x;           // 0..4095 over sim_cat
    const int self = row & 2047;
    const int t = threadIdx.x;
    const f32x4* p = (const f32x4*)(sim + (size_t)row * 2048);
    f32x4 a = p[t * 2], b = p[t * 2 + 1];
    float best = -3.0e38f; int bi = 0;
#pragma unroll
    for (int j = 0; j < 4; ++j) {
        int c = t * 8 + j;
        if (c != self && a[j] > best) { best = a[j]; bi = c; }
    }
#pragma unroll
    for (int j = 0; j < 4; ++j) {
        int c = t * 8 + 4 + j;
        if (c != self && b[j] > best) { best = b[j]; bi = c; }
    }
    __shared__ float BV[256]; __shared__ int BI[256];
    BV[t] = best; BI[t] = bi;
    __syncthreads();
    for (int off = 128; off; off >>= 1) {
        if (t < off) {
            float v2 = BV[t + off]; int i2 = BI[t + off];
            if (v2 > BV[t] || (v2 == BV[t] && i2 < BI[t])) { BV[t] = v2; BI[t] = i2; }
        }
        __syncthreads();
    }
    if (t == 0) y[row] = BI[0];
}

// ---------------------------------------------------------------- connected components via min-propagation (1 block/branch)
__global__ __launch_bounds__(1024) void cc_labels(const int* __restrict__ yg, int* __restrict__ labg)
{
    __shared__ int A_[2048];
    __shared__ int Bn[2048];
    __shared__ int Y_[2048];
    const int br = blockIdx.x;
    const int t = threadIdx.x;
    for (int i = t; i < 2048; i += 1024) { Y_[i] = yg[br * 2048 + i]; A_[i] = i; }
    __syncthreads();
    for (int it = 0; it < 32; ++it) {
        for (int i = t; i < 2048; i += 1024) Bn[i] = min(A_[i], A_[Y_[i]]);   // ln = min(l, l[y])
        __syncthreads();
        for (int i = t; i < 2048; i += 1024) atomicMin(&Bn[Y_[i]], A_[i]);    // ln = ln.at[y].min(l)
        __syncthreads();
        for (int i = t; i < 2048; i += 1024) { int b = Bn[i]; A_[i] = min(b, Bn[b]); } // pointer jump
        __syncthreads();
    }
    for (int i = t; i < 2048; i += 1024) labg[br * 2048 + i] = A_[i];
}

// ---------------------------------------------------------------- per-row contrastive term: lse - possum/poscnt
__global__ __launch_bounds__(256) void loss_rows(const float* __restrict__ sim, const int* __restrict__ labels,
                                                 float* __restrict__ terms)
{
    const int row = blockIdx.x;
    const int br  = row >> 11;
    const int* lab = labels + ((1 - br) << 11);  // mask from the OTHER branch's labels
    const int self = row & 2047;
    const int li = lab[self];
    const int t = threadIdx.x;
    const f32x4* p = (const f32x4*)(sim + (size_t)row * 2048);
    f32x4 a = p[t * 2], b = p[t * 2 + 1];
    float se = 0.f, ps = 0.f; int pc = 0;
#pragma unroll
    for (int j = 0; j < 8; ++j) {
        const int c = t * 8 + j;
        const float v = (j < 4) ? a[j] : b[j - 4];
        if (c == self) continue;
        const float lg = v * 10.0f;   // 1/T
        se += expf(lg);
        if (lab[c] == li) { ps += lg; pc++; }
    }
    __shared__ float SE[256], PS[256]; __shared__ int PC[256];
    SE[t] = se; PS[t] = ps; PC[t] = pc;
    __syncthreads();
    for (int off = 128; off; off >>= 1) {
        if (t < off) { SE[t] += SE[t + off]; PS[t] += PS[t + off]; PC[t] += PC[t + off]; }
        __syncthreads();
    }
    if (t == 0) terms[row] = logf(SE[0]) - PS[0] / (float)PC[0];
}

// ---------------------------------------------------------------- final deterministic reduce
__global__ __launch_bounds__(1024) void final_reduce(const float* __restrict__ terms, float* __restrict__ out)
{
    const int t = threadIdx.x;
    float s = terms[t] + terms[t + 1024] + terms[t + 2048] + terms[t + 3072];
    __shared__ float S[1024];
    S[t] = s;
    __syncthreads();
    for (int off = 512; off; off >>= 1) { if (t < off) S[t] += S[t + off]; __syncthreads(); }
    if (t == 0) out[0] = S[0] * (1.0f / 4096.0f);   // (L1+L2)/2, each mean over 2048 rows
}

// ---------------------------------------------------------------- launch
extern "C" void kernel_launch(void* const* d_in, const int* in_sizes, int n_in,
                              void* d_out, int out_size, void* d_ws, size_t ws_size,
                              hipStream_t stream)
{
    const float* x1    = (const float*)d_in[0];
    const float* x2    = (const float*)d_in[1];
    const float* W1    = (const float*)d_in[2];
    const float* b1    = (const float*)d_in[3];
    const float* gamma = (const float*)d_in[4];
    const float* beta  = (const float*)d_in[5];
    const float* W2    = (const float*)d_in[6];
    const float* b2    = (const float*)d_in[7];

    char* ws = (char*)d_ws;
    const size_t MB = 1024ull * 1024ull;
    const size_t NN = 2048ull * 2048ull;
    // Region plan (reuse as regions go dead):
    //  [0,8M)   W1b      (dead after GEMM_A)
    //  [8,16M)  W2b      (dead after GEMM_B)
    //  [16,32M) xcatb -> hnb (dead after GEMM_B)
    //  [32,64M) h -> o   (dead after rownorm)
    //  [0,32M)  sim_cat  (written by GEMM_C, after the above are dead)
    //  [64,80M) featb
    //  [80M..)  small buffers
    bf16_t* W1b    = (bf16_t*)(ws + 0);
    bf16_t* W2b    = (bf16_t*)(ws + 8 * MB);
    bf16_t* xcatb  = (bf16_t*)(ws + 16 * MB);
    bf16_t* hnb    = (bf16_t*)(ws + 16 * MB);
    float*  hbuf   = (float*)(ws + 32 * MB);
    float*  sim    = (float*)(ws + 0);
    bf16_t* featb  = (bf16_t*)(ws + 64 * MB);
    float*  psum   = (float*)(ws + 80 * MB);
    float*  psum2  = psum + 4 * 4096;
    float*  mu     = psum2 + 4 * 4096;
    float*  rinv   = mu + 4096;
    int*    yidx   = (int*)(rinv + 4096);
    int*    labels = yidx + 4096;
    float*  terms  = (float*)(labels + 4096);

    // casts to bf16 (x1;x2 concatenated as one 4096x2048 batch)
    cast_bf16_k<<<4096, 256, 0, stream>>>(x1, xcatb);
    cast_bf16_k<<<4096, 256, 0, stream>>>(x2, xcatb + NN);
    cast_bf16_k<<<4096, 256, 0, stream>>>(W1, W1b);
    cast_bf16_k<<<4096, 256, 0, stream>>>(W2, W2b);

    // h = xcat @ W1^T + b1   (M=4096, N=2048, K=2048)
    gemm_bt<<<dim3(16, 32), 256, 0, stream>>>(xcatb, W1b, b1, hbuf, 2048, 2048, 1 << 30, 0);

    // BN (per-branch batch stats) + ReLU + bf16
    bn_part<<<256, 256, 0, stream>>>(hbuf, psum, psum2);
    bn_final<<<16, 256, 0, stream>>>(psum, psum2, mu, rinv);
    bn_apply<<<8192, 256, 0, stream>>>(hbuf, mu, rinv, gamma, beta, hnb);

    // o = hn @ W2^T + b2  (overwrites h region)
    gemm_bt<<<dim3(16, 32), 256, 0, stream>>>(hnb, W2b, b2, hbuf, 2048, 2048, 1 << 30, 0);

    // feat = normalize(o) -> bf16
    rownorm<<<4096, 256, 0, stream>>>(hbuf, featb);

    // sim_cat = [feat1@feat1^T ; feat2@feat2^T]  (B operand batched per 2048-row block)
    gemm_bt<<<dim3(16, 32), 256, 0, stream>>>(featb, featb, nullptr, sim, 2048, 2048, 2048, (long long)NN);

    // kNN graph -> connected components -> per-row loss terms -> scalar
    rowargmax<<<4096, 256, 0, stream>>>(sim, yidx);
    cc_labels<<<2, 1024, 0, stream>>>(yidx, labels);
    loss_rows<<<4096, 256, 0, stream>>>(sim, labels, terms);
    final_reduce<<<1, 1024, 0, stream>>>(terms, (float*)d_out);
}